// Round 7
// baseline (694.651 us; speedup 1.0000x reference)
//
#include <hip/hip_runtime.h>

typedef unsigned short ushort_t;
typedef __attribute__((ext_vector_type(8))) __bf16 bf16x8;
typedef __attribute__((ext_vector_type(4))) float f32x4;

#define NT 8192     // tokens
#define NE 8        // experts
#define ND 1024     // model dim
#define NF 4096     // ffn dim
#define CAP 1280    // capacity per expert

// Blocked operand layout (BK=32): per expert, elem (row,k) at [(k>>5)][row][k&31]
// -> one k-block row = 64B contiguous; one 128-row K-step tile = 8KB contiguous.

// ws layout (bytes)
#define W1T_OFF 0u
#define W2T_OFF 67108864u
#define XD_OFF  134217728u
#define H_OFF   155189248u
#define EIDX_OFF 239075328u
#define TPROB_OFF 239108096u
#define TSLOT_OFF 239140864u

__device__ __forceinline__ unsigned short f2bf(float f) {
  unsigned int u = __float_as_uint(f);
  unsigned int r = (u + 0x7fffu + ((u >> 16) & 1u)) >> 16;
  return (unsigned short)r;
}

// ---------------- zero out ----------------
__global__ void zero_kernel(float* __restrict__ p, long n) {
  long i = (long)blockIdx.x * blockDim.x + threadIdx.x;
  long stride = (long)gridDim.x * blockDim.x;
  float4* p4 = (float4*)p;
  long n4 = n >> 2;
  for (long j = i; j < n4; j += stride) p4[j] = make_float4(0.f, 0.f, 0.f, 0.f);
}

// ---------------- routing: one wave per token ----------------
__global__ void route_kernel(const float* __restrict__ x, const float* __restrict__ gw,
                             const float* __restrict__ gb, int* __restrict__ eidx,
                             float* __restrict__ tprob) {
  int wid = threadIdx.x >> 6, lane = threadIdx.x & 63;
  int t = blockIdx.x * 4 + wid;
  const float4* xv = (const float4*)(x + (size_t)t * ND);
  float acc[NE];
#pragma unroll
  for (int e = 0; e < NE; ++e) acc[e] = 0.f;
#pragma unroll
  for (int c = 0; c < 4; ++c) {
    float4 xx = xv[lane * 4 + c];
#pragma unroll
    for (int e = 0; e < NE; ++e) {
      float4 wv = *(const float4*)(gw + (size_t)e * ND + lane * 16 + c * 4);
      acc[e] += xx.x * wv.x + xx.y * wv.y + xx.z * wv.z + xx.w * wv.w;
    }
  }
#pragma unroll
  for (int off = 32; off >= 1; off >>= 1) {
#pragma unroll
    for (int e = 0; e < NE; ++e) acc[e] += __shfl_xor(acc[e], off, 64);
  }
  if (lane == 0) {
    float l[NE];
#pragma unroll
    for (int e = 0; e < NE; ++e) l[e] = acc[e] + gb[e];
    float mx = l[0];
    int am = 0;
#pragma unroll
    for (int e = 1; e < NE; ++e) {
      if (l[e] > mx) { mx = l[e]; am = e; }
    }
    float s = 0.f;
#pragma unroll
    for (int e = 0; e < NE; ++e) s += __expf(l[e] - mx);
    eidx[t] = am;
    tprob[t] = 1.0f / s;
  }
}

// ---------------- capacity scan (single block, order-preserving, wave-shuffle) ----------------
__global__ void scan_kernel(const int* __restrict__ eidx, int* __restrict__ tslot) {
  __shared__ unsigned long long w0[16], w1[16];
  int tid = threadIdx.x;
  int lane = tid & 63, wid = tid >> 6;
  for (int i = tid; i < NE * CAP; i += 1024) tslot[i] = -1;
  int myE[8];
  unsigned long long a = 0, b = 0;
#pragma unroll
  for (int i = 0; i < 8; ++i) {
    int e = eidx[tid * 8 + i];
    myE[i] = e;
    if (e < 4) a += 1ULL << (16 * e);
    else       b += 1ULL << (16 * (e - 4));
  }
  unsigned long long ia = a, ib = b;
#pragma unroll
  for (int off = 1; off < 64; off <<= 1) {
    unsigned long long pa = __shfl_up(ia, off, 64);
    unsigned long long pb = __shfl_up(ib, off, 64);
    if (lane >= off) { ia += pa; ib += pb; }
  }
  if (lane == 63) { w0[wid] = ia; w1[wid] = ib; }
  __syncthreads();
  if (wid == 0 && lane < 16) {
    unsigned long long va = w0[lane], vb = w1[lane];
#pragma unroll
    for (int off = 1; off < 16; off <<= 1) {
      unsigned long long pa = __shfl_up(va, off, 64);
      unsigned long long pb = __shfl_up(vb, off, 64);
      if (lane >= off) { va += pa; vb += pb; }
    }
    w0[lane] = va; w1[lane] = vb;
  }
  __syncthreads();
  unsigned long long ea = ia - a, eb = ib - b;
  if (wid > 0) { ea += w0[wid - 1]; eb += w1[wid - 1]; }
  int base[NE];
#pragma unroll
  for (int e = 0; e < 4; ++e) {
    base[e]     = (int)((ea >> (16 * e)) & 0xffffULL);
    base[4 + e] = (int)((eb >> (16 * e)) & 0xffffULL);
  }
#pragma unroll
  for (int i = 0; i < 8; ++i) {
    int t = tid * 8 + i;
    int e = myE[i];
    int p = base[e]++;
    if (p < CAP) tslot[e * CAP + p] = t;
  }
}

// ---------------- gather tokens -> bf16 dispatch buffer (blocked-32) ----------------
__global__ void gather_kernel(const float* __restrict__ x, const int* __restrict__ tslot,
                              ushort_t* __restrict__ Xd) {
  int slot = blockIdx.x;
  int e = slot / CAP, row = slot % CAP;
  int t = tslot[slot];
  int d = threadIdx.x * 4;
  ushort4 u;
  if (t >= 0) {
    float4 v = *(const float4*)(x + (size_t)t * ND + d);
    u.x = f2bf(v.x); u.y = f2bf(v.y); u.z = f2bf(v.z); u.w = f2bf(v.w);
  } else {
    u.x = 0; u.y = 0; u.z = 0; u.w = 0;
  }
  ushort_t* dst = Xd + (size_t)e * CAP * ND + (size_t)(d >> 5) * CAP * 32 + row * 32 + (d & 31);
  *(ushort4*)dst = u;
}

// ---------------- transpose+convert: W [E][K][N] fp32 -> Wt blocked-32 bf16 ----------------
__global__ void transpose_kernel(const float* __restrict__ W, ushort_t* __restrict__ Wt,
                                 int K, int N) {
  __shared__ float tile[64][65];
  int e = blockIdx.z;
  int n0 = blockIdx.x * 64, k0 = blockIdx.y * 64;
  const float* We = W + (size_t)e * K * N;
  ushort_t* Wte = Wt + (size_t)e * K * N;
  for (int i = threadIdx.x; i < 1024; i += 256) {
    int r = i >> 4, c4 = (i & 15) << 2;
    float4 v = *(const float4*)(We + (size_t)(k0 + r) * N + n0 + c4);
    tile[r][c4] = v.x; tile[r][c4 + 1] = v.y; tile[r][c4 + 2] = v.z; tile[r][c4 + 3] = v.w;
  }
  __syncthreads();
  for (int i = threadIdx.x; i < 512; i += 256) {
    int n = i >> 3, kq = (i & 7) << 3;       // kq in {0,8,...,56}
    uint4 u;
    u.x = (unsigned)f2bf(tile[kq + 0][n]) | ((unsigned)f2bf(tile[kq + 1][n]) << 16);
    u.y = (unsigned)f2bf(tile[kq + 2][n]) | ((unsigned)f2bf(tile[kq + 3][n]) << 16);
    u.z = (unsigned)f2bf(tile[kq + 4][n]) | ((unsigned)f2bf(tile[kq + 5][n]) << 16);
    u.w = (unsigned)f2bf(tile[kq + 6][n]) | ((unsigned)f2bf(tile[kq + 7][n]) << 16);
    size_t dst = (size_t)((k0 + kq) >> 5) * N * 32 + (size_t)(n0 + n) * 32 + (kq & 31);
    *(uint4*)(Wte + dst) = u;
  }
}

// ---------------- staging one K-step: A[128][32] 8KB + B[128][32] 8KB ----------------
// LDS line = 128B holds rows (r, r+64); XOR ((line&7)<<4) applied via pre-swizzled
// global source (linear LDS dest for global_load_lds). 256 threads x 4 loads = 16KB.
__device__ __forceinline__ void stage32(const char* slabA, const char* slabB,
                                        char* sbuf, int tid) {
#pragma unroll
  for (int r = 0; r < 2; ++r) {
    int o = r * 4096 + tid * 16;
    int line = o >> 7, inner = o & 127;
    int lg = inner ^ ((line & 7) << 4);
    int grow = ((lg >> 6) << 6) | line;     // h*64 + line
    __builtin_amdgcn_global_load_lds(
        (const __attribute__((address_space(1))) void*)(slabA + grow * 64 + (lg & 63)),
        (__attribute__((address_space(3))) void*)(sbuf + o), 16, 0, 0);
  }
#pragma unroll
  for (int r = 0; r < 2; ++r) {
    int o = r * 4096 + tid * 16;
    int line = o >> 7, inner = o & 127;
    int lg = inner ^ ((line & 7) << 4);
    int grow = ((lg >> 6) << 6) | line;
    __builtin_amdgcn_global_load_lds(
        (const __attribute__((address_space(1))) void*)(slabB + grow * 64 + (lg & 63)),
        (__attribute__((address_space(3))) void*)(sbuf + 8192 + o), 16, 0, 0);
  }
}

// ---------------- GEMM mainloop: 2-phase double-buffer, BK=32, 32KB LDS ----------------
// 128x128 tile, 4 waves (2Mx2N), per-wave 64x64 (acc[4][4], 16 MFMA/step).
// stage(t+1) issued BEFORE compute(t); one __syncthreads per step (implicit
// vmcnt(0)+lgkmcnt(0) drain covers prefetch + LDS reads). 5 blocks/CU hide the drain.
__device__ __forceinline__ void gemm_mainloop32(const char* __restrict__ slabA,
                                                const char* __restrict__ slabB,
                                                int nkt, size_t aBlk, size_t bBlk,
                                                char* smem, f32x4 acc[4][4]) {
  const int tid = threadIdx.x;
  const int lane = tid & 63, wid = tid >> 6;
  const int wr = wid >> 1, wc = wid & 1;
  const int lr = lane & 15, lq = lane >> 4;

  int aOff[4], bOff[4];
#pragma unroll
  for (int m = 0; m < 4; ++m) {
    int line = m * 16 + lr;
    aOff[m] = line * 128 + ((wr * 64 + lq * 16) ^ ((lr & 7) << 4));
  }
#pragma unroll
  for (int n = 0; n < 4; ++n) {
    int line = n * 16 + lr;
    bOff[n] = 8192 + line * 128 + ((wc * 64 + lq * 16) ^ ((lr & 7) << 4));
  }

  stage32(slabA, slabB, smem, tid);
  __syncthreads();
  int cur = 0;
  for (int kb = 0; kb < nkt; ++kb) {
    if (kb + 1 < nkt)
      stage32(slabA + (size_t)(kb + 1) * aBlk, slabB + (size_t)(kb + 1) * bBlk,
              smem + (cur ^ 1) * 16384, tid);
    char* base = smem + cur * 16384;
    bf16x8 av[4], bv[4];
#pragma unroll
    for (int m = 0; m < 4; ++m) av[m] = *(const bf16x8*)(base + aOff[m]);
#pragma unroll
    for (int n = 0; n < 4; ++n) bv[n] = *(const bf16x8*)(base + bOff[n]);
    __builtin_amdgcn_s_setprio(1);
#pragma unroll
    for (int m = 0; m < 4; ++m)
#pragma unroll
      for (int n = 0; n < 4; ++n)
        acc[m][n] = __builtin_amdgcn_mfma_f32_16x16x32_bf16(av[m], bv[n], acc[m][n], 0, 0, 0);
    __builtin_amdgcn_s_setprio(0);
    __syncthreads();
    cur ^= 1;
  }
}

// ---------------- GEMM1: H_b = relu(Xd_b @ W1t_b^T + b1) ----------------
// grid 2560 = 8e x (32n x 10m); e=bid&7 pins expert to XCD; m-fastest (B-tile L2 reuse).
__global__ __launch_bounds__(256, 5) void gemm1_kernel(const ushort_t* __restrict__ Xd,
                                                       const ushort_t* __restrict__ W1t,
                                                       const float* __restrict__ b1,
                                                       ushort_t* __restrict__ H) {
  int e = blockIdx.x & 7;
  int idx = blockIdx.x >> 3;          // 0..319
  int bn0 = (idx / 10) * 128;
  int bm0 = (idx % 10) * 128;
  const char* slabA = (const char*)(Xd + (size_t)e * CAP * ND) + (size_t)bm0 * 64;
  const char* slabB = (const char*)(W1t + (size_t)e * NF * ND) + (size_t)bn0 * 64;
  __shared__ __align__(16) char smem[32768];
  f32x4 zero4 = {0.f, 0.f, 0.f, 0.f};
  f32x4 acc[4][4];
#pragma unroll
  for (int m = 0; m < 4; ++m)
#pragma unroll
    for (int n = 0; n < 4; ++n) acc[m][n] = zero4;
  gemm_mainloop32(slabA, slabB, ND / 32, (size_t)CAP * 64, (size_t)NF * 64, smem, acc);
  const int lane = threadIdx.x & 63, wid = threadIdx.x >> 6;
  const int wr = wid >> 1, wc = wid & 1;
  const int lr = lane & 15, lq = lane >> 4;
  ushort_t* He = H + (size_t)e * CAP * NF;
#pragma unroll
  for (int m = 0; m < 4; ++m) {
#pragma unroll
    for (int n = 0; n < 4; ++n) {
      int col = bn0 + wc * 64 + n * 16 + lr;
      float bias = b1[(size_t)e * NF + col];
      ushort_t* dst = He + (size_t)(col >> 5) * (CAP * 32) + (col & 31);
#pragma unroll
      for (int j = 0; j < 4; ++j) {
        int row = bm0 + wr * 64 + m * 16 + lq * 4 + j;
        float v = acc[m][n][j] + bias;
        v = fmaxf(v, 0.f);
        dst[(size_t)row * 32] = f2bf(v);
      }
    }
  }
}

// ---------------- GEMM2 (no split): out[token] = (H_b @ W2t_b^T + b2) * tprob ----------------
// grid 640 = 8e x (8n x 10m); K=4096 (128 steps); direct scatter stores, no atomics.
__global__ __launch_bounds__(256, 5) void gemm2_kernel(const ushort_t* __restrict__ H,
                                                       const ushort_t* __restrict__ W2t,
                                                       const float* __restrict__ b2,
                                                       const int* __restrict__ tslot,
                                                       const float* __restrict__ tprob,
                                                       float* __restrict__ out) {
  int e = blockIdx.x & 7;
  int idx = blockIdx.x >> 3;          // 0..79
  int bn0 = (idx / 10) * 128;
  int bm0 = (idx % 10) * 128;
  const char* slabA = (const char*)(H + (size_t)e * CAP * NF) + (size_t)bm0 * 64;
  const char* slabB = (const char*)(W2t + (size_t)e * ND * NF) + (size_t)bn0 * 64;
  __shared__ __align__(16) char smem[32768];
  f32x4 zero4 = {0.f, 0.f, 0.f, 0.f};
  f32x4 acc[4][4];
#pragma unroll
  for (int m = 0; m < 4; ++m)
#pragma unroll
    for (int n = 0; n < 4; ++n) acc[m][n] = zero4;
  gemm_mainloop32(slabA, slabB, NF / 32, (size_t)CAP * 64, (size_t)ND * 64, smem, acc);
  const int lane = threadIdx.x & 63, wid = threadIdx.x >> 6;
  const int wr = wid >> 1, wc = wid & 1;
  const int lr = lane & 15, lq = lane >> 4;
  float bias[4];
#pragma unroll
  for (int n = 0; n < 4; ++n)
    bias[n] = b2[(size_t)e * ND + bn0 + wc * 64 + n * 16 + lr];
#pragma unroll
  for (int m = 0; m < 4; ++m) {
#pragma unroll
    for (int j = 0; j < 4; ++j) {
      int row = bm0 + wr * 64 + m * 16 + lq * 4 + j;
      int t = tslot[e * CAP + row];
      if (t >= 0) {
        float p = tprob[t];
#pragma unroll
        for (int n = 0; n < 4; ++n) {
          int col = bn0 + wc * 64 + n * 16 + lr;
          out[(size_t)t * ND + col] = (acc[m][n][j] + bias[n]) * p;
        }
      }
    }
  }
}

extern "C" void kernel_launch(void* const* d_in, const int* in_sizes, int n_in,
                              void* d_out, int out_size, void* d_ws, size_t ws_size,
                              hipStream_t stream) {
  const float* h  = (const float*)d_in[0];
  const float* gw = (const float*)d_in[1];
  const float* gb = (const float*)d_in[2];
  const float* w1 = (const float*)d_in[3];
  const float* b1 = (const float*)d_in[4];
  const float* w2 = (const float*)d_in[5];
  const float* b2 = (const float*)d_in[6];
  float* out = (float*)d_out;
  char* ws = (char*)d_ws;

  ushort_t* W1t = (ushort_t*)(ws + W1T_OFF);
  ushort_t* W2t = (ushort_t*)(ws + W2T_OFF);
  ushort_t* Xd  = (ushort_t*)(ws + XD_OFF);
  ushort_t* H   = (ushort_t*)(ws + H_OFF);
  int* eidx     = (int*)(ws + EIDX_OFF);
  float* tprob  = (float*)(ws + TPROB_OFF);
  int* tslot    = (int*)(ws + TSLOT_OFF);

  zero_kernel<<<1024, 256, 0, stream>>>(out, (long)out_size);
  route_kernel<<<NT / 4, 256, 0, stream>>>(h, gw, gb, eidx, tprob);
  scan_kernel<<<1, 1024, 0, stream>>>(eidx, tslot);
  gather_kernel<<<NE * CAP, 256, 0, stream>>>(h, tslot, Xd);
  transpose_kernel<<<dim3(NF / 64, ND / 64, NE), 256, 0, stream>>>(w1, W1t, ND, NF);
  transpose_kernel<<<dim3(ND / 64, NF / 64, NE), 256, 0, stream>>>(w2, W2t, NF, ND);
  gemm1_kernel<<<(NF / 128) * (CAP / 128) * NE, 256, 0, stream>>>(Xd, W1t, b1, H);
  gemm2_kernel<<<(ND / 128) * (CAP / 128) * NE, 256, 0, stream>>>(H, W2t, b2, tslot, tprob, out);
}

// Round 8
// 412.582 us; speedup vs baseline: 1.6837x; 1.6837x over previous
//
#include <hip/hip_runtime.h>

typedef unsigned short ushort_t;
typedef __attribute__((ext_vector_type(8))) __bf16 bf16x8;
typedef __attribute__((ext_vector_type(4))) float f32x4;

#define NT 8192     // tokens
#define NE 8        // experts
#define ND 1024     // model dim
#define NF 4096     // ffn dim
#define CAP 1280    // capacity per expert
#define KSPLIT 2    // split-K for GEMM2

// Blocked operand layout (BK=64): per expert, elem (row,k) at [(k>>6)][row][k&63]
// -> one 128-row x 64-k tile = 16KB contiguous.

// ws layout (bytes)
#define W1T_OFF 0u
#define W2T_OFF 67108864u
#define XD_OFF  134217728u
#define H_OFF   155189248u
#define EIDX_OFF 239075328u
#define TPROB_OFF 239108096u
#define TSLOT_OFF 239140864u

__device__ __forceinline__ unsigned short f2bf(float f) {
  unsigned int u = __float_as_uint(f);
  unsigned int r = (u + 0x7fffu + ((u >> 16) & 1u)) >> 16;
  return (unsigned short)r;
}

// bijective XCD-chunked remap (m204): contiguous chunk of tiles per XCD
__device__ __forceinline__ int xcd_swizzle(int wgid, int nwg) {
  int q = nwg >> 3, r = nwg & 7;
  int xcd = wgid & 7, idx = wgid >> 3;
  return (xcd < r ? xcd * (q + 1) : r * (q + 1) + (xcd - r) * q) + idx;
}

// ---------------- zero out ----------------
__global__ void zero_kernel(float* __restrict__ p, long n) {
  long i = (long)blockIdx.x * blockDim.x + threadIdx.x;
  long stride = (long)gridDim.x * blockDim.x;
  float4* p4 = (float4*)p;
  long n4 = n >> 2;
  for (long j = i; j < n4; j += stride) p4[j] = make_float4(0.f, 0.f, 0.f, 0.f);
}

// ---------------- routing: one wave per token ----------------
__global__ void route_kernel(const float* __restrict__ x, const float* __restrict__ gw,
                             const float* __restrict__ gb, int* __restrict__ eidx,
                             float* __restrict__ tprob) {
  int wid = threadIdx.x >> 6, lane = threadIdx.x & 63;
  int t = blockIdx.x * 4 + wid;
  const float4* xv = (const float4*)(x + (size_t)t * ND);
  float acc[NE];
#pragma unroll
  for (int e = 0; e < NE; ++e) acc[e] = 0.f;
#pragma unroll
  for (int c = 0; c < 4; ++c) {
    float4 xx = xv[lane * 4 + c];
#pragma unroll
    for (int e = 0; e < NE; ++e) {
      float4 wv = *(const float4*)(gw + (size_t)e * ND + lane * 16 + c * 4);
      acc[e] += xx.x * wv.x + xx.y * wv.y + xx.z * wv.z + xx.w * wv.w;
    }
  }
#pragma unroll
  for (int off = 32; off >= 1; off >>= 1) {
#pragma unroll
    for (int e = 0; e < NE; ++e) acc[e] += __shfl_xor(acc[e], off, 64);
  }
  if (lane == 0) {
    float l[NE];
#pragma unroll
    for (int e = 0; e < NE; ++e) l[e] = acc[e] + gb[e];
    float mx = l[0];
    int am = 0;
#pragma unroll
    for (int e = 1; e < NE; ++e) {
      if (l[e] > mx) { mx = l[e]; am = e; }   // first occurrence kept on ties
    }
    float s = 0.f;
#pragma unroll
    for (int e = 0; e < NE; ++e) s += __expf(l[e] - mx);
    eidx[t] = am;
    tprob[t] = 1.0f / s;
  }
}

// ---------------- capacity scan (single block, order-preserving, wave-shuffle) ----------------
__global__ void scan_kernel(const int* __restrict__ eidx, int* __restrict__ tslot) {
  __shared__ unsigned long long w0[16], w1[16];
  int tid = threadIdx.x;
  int lane = tid & 63, wid = tid >> 6;
  for (int i = tid; i < NE * CAP; i += 1024) tslot[i] = -1;
  int myE[8];
  unsigned long long a = 0, b = 0;
#pragma unroll
  for (int i = 0; i < 8; ++i) {
    int e = eidx[tid * 8 + i];
    myE[i] = e;
    if (e < 4) a += 1ULL << (16 * e);
    else       b += 1ULL << (16 * (e - 4));
  }
  unsigned long long ia = a, ib = b;
#pragma unroll
  for (int off = 1; off < 64; off <<= 1) {
    unsigned long long pa = __shfl_up(ia, off, 64);
    unsigned long long pb = __shfl_up(ib, off, 64);
    if (lane >= off) { ia += pa; ib += pb; }
  }
  if (lane == 63) { w0[wid] = ia; w1[wid] = ib; }
  __syncthreads();
  if (wid == 0 && lane < 16) {
    unsigned long long va = w0[lane], vb = w1[lane];
#pragma unroll
    for (int off = 1; off < 16; off <<= 1) {
      unsigned long long pa = __shfl_up(va, off, 64);
      unsigned long long pb = __shfl_up(vb, off, 64);
      if (lane >= off) { va += pa; vb += pb; }
    }
    w0[lane] = va; w1[lane] = vb;
  }
  __syncthreads();
  unsigned long long ea = ia - a, eb = ib - b;
  if (wid > 0) { ea += w0[wid - 1]; eb += w1[wid - 1]; }
  int base[NE];
#pragma unroll
  for (int e = 0; e < 4; ++e) {
    base[e]     = (int)((ea >> (16 * e)) & 0xffffULL);
    base[4 + e] = (int)((eb >> (16 * e)) & 0xffffULL);
  }
#pragma unroll
  for (int i = 0; i < 8; ++i) {
    int t = tid * 8 + i;
    int e = myE[i];
    int p = base[e]++;
    if (p < CAP) tslot[e * CAP + p] = t;
  }
}

// ---------------- gather tokens -> bf16 dispatch buffer (blocked-64) ----------------
__global__ void gather_kernel(const float* __restrict__ x, const int* __restrict__ tslot,
                              ushort_t* __restrict__ Xd) {
  int slot = blockIdx.x;
  int e = slot / CAP, row = slot % CAP;
  int t = tslot[slot];
  int d = threadIdx.x * 4;
  ushort4 u;
  if (t >= 0) {
    float4 v = *(const float4*)(x + (size_t)t * ND + d);
    u.x = f2bf(v.x); u.y = f2bf(v.y); u.z = f2bf(v.z); u.w = f2bf(v.w);
  } else {
    u.x = 0; u.y = 0; u.z = 0; u.w = 0;
  }
  ushort_t* dst = Xd + (size_t)e * CAP * ND + (size_t)(d >> 6) * CAP * 64 + row * 64 + (d & 63);
  *(ushort4*)dst = u;
}

// ---------------- transpose+convert: W [E][K][N] fp32 -> Wt_b [E][K/64][N][64] bf16 ----------------
__global__ void transpose_kernel(const float* __restrict__ W, ushort_t* __restrict__ Wt,
                                 int K, int N) {
  __shared__ float tile[64][65];
  int e = blockIdx.z;
  int n0 = blockIdx.x * 64, k0 = blockIdx.y * 64;
  const float* We = W + (size_t)e * K * N;
  ushort_t* Wte = Wt + (size_t)e * K * N + (size_t)(k0 >> 6) * N * 64;
  for (int i = threadIdx.x; i < 1024; i += 256) {
    int r = i >> 4, c4 = (i & 15) << 2;
    float4 v = *(const float4*)(We + (size_t)(k0 + r) * N + n0 + c4);
    tile[r][c4] = v.x; tile[r][c4 + 1] = v.y; tile[r][c4 + 2] = v.z; tile[r][c4 + 3] = v.w;
  }
  __syncthreads();
  for (int i = threadIdx.x; i < 512; i += 256) {
    int n = i >> 3, kq = (i & 7) << 3;
    uint4 u;
    u.x = (unsigned)f2bf(tile[kq + 0][n]) | ((unsigned)f2bf(tile[kq + 1][n]) << 16);
    u.y = (unsigned)f2bf(tile[kq + 2][n]) | ((unsigned)f2bf(tile[kq + 3][n]) << 16);
    u.z = (unsigned)f2bf(tile[kq + 4][n]) | ((unsigned)f2bf(tile[kq + 5][n]) << 16);
    u.w = (unsigned)f2bf(tile[kq + 6][n]) | ((unsigned)f2bf(tile[kq + 7][n]) << 16);
    *(uint4*)(Wte + (size_t)(n0 + n) * 64 + kq) = u;
  }
}

// ---------------- GEMM mainloop: m97 single-buffer 2-barrier, BK=64, 32KB LDS ----------------
// 128x128 tile, 4 waves (2Mx2N). Per K-step: stage 16KB A + 16KB B (global_load_lds w16,
// pre-swizzled source for ((row&7)<<4) XOR) -> syncthreads -> 32 MFMA -> syncthreads.
// 3 blocks/CU residency hides the per-step drain (m97: 874-912 TF at this structure).
__device__ __forceinline__ void gemm_mainloop(const char* __restrict__ Ab,
                                              const char* __restrict__ Bb,
                                              int kbStart, int kbEnd,
                                              size_t aBlkB, size_t bBlkB,
                                              int bm0, int bn0, char* smem,
                                              f32x4 acc[4][4]) {
  const int tid = threadIdx.x;
  const int lane = tid & 63, wid = tid >> 6;
  const int wr = wid >> 1, wc = wid & 1;
  const int lr = lane & 15, lq = lane >> 4;
  char* sA = smem;
  char* sB = smem + 16384;
  for (int kb = kbStart; kb < kbEnd; ++kb) {
    const char* bA = Ab + (size_t)kb * aBlkB + (size_t)bm0 * 128;
    const char* bB = Bb + (size_t)kb * bBlkB + (size_t)bn0 * 128;
#pragma unroll
    for (int r = 0; r < 4; ++r) {
      int o = r * 4096 + tid * 16;                      // physical dest byte
      int row = o >> 7;
      int src = (o & ~127) | ((o & 127) ^ ((row & 7) << 4));  // pre-swizzled source
      __builtin_amdgcn_global_load_lds((const __attribute__((address_space(1))) void*)(bA + src),
                                       (__attribute__((address_space(3))) void*)(sA + o),
                                       16, 0, 0);
      __builtin_amdgcn_global_load_lds((const __attribute__((address_space(1))) void*)(bB + src),
                                       (__attribute__((address_space(3))) void*)(sB + o),
                                       16, 0, 0);
    }
    __syncthreads();
    __builtin_amdgcn_s_setprio(1);
#pragma unroll
    for (int kk = 0; kk < 2; ++kk) {
      const int kbyte = kk * 64 + lq * 16;
      bf16x8 av[4], bv[4];
#pragma unroll
      for (int m = 0; m < 4; ++m) {
        int row = wr * 64 + m * 16 + lr;
        int off = ((row << 7) + kbyte) ^ ((lr & 7) << 4);
        av[m] = *(const bf16x8*)(sA + off);
      }
#pragma unroll
      for (int n = 0; n < 4; ++n) {
        int row = wc * 64 + n * 16 + lr;
        int off = ((row << 7) + kbyte) ^ ((lr & 7) << 4);
        bv[n] = *(const bf16x8*)(sB + off);
      }
#pragma unroll
      for (int m = 0; m < 4; ++m)
#pragma unroll
        for (int n = 0; n < 4; ++n)
          acc[m][n] = __builtin_amdgcn_mfma_f32_16x16x32_bf16(av[m], bv[n], acc[m][n], 0, 0, 0);
    }
    __builtin_amdgcn_s_setprio(0);
    __syncthreads();
  }
}

// ---------------- GEMM1: H_b = relu(Xd_b @ W1t_b^T + b1), bf16 blocked out ----------------
// grid 2560; XCD-chunked: one expert per XCD, m-fastest (10 blocks share a B-panel).
__global__ __launch_bounds__(256) void gemm1_kernel(const ushort_t* __restrict__ Xd,
                                                    const ushort_t* __restrict__ W1t,
                                                    const float* __restrict__ b1,
                                                    ushort_t* __restrict__ H) {
  int swz = xcd_swizzle(blockIdx.x, (NF / 128) * (CAP / 128) * NE);
  int e = swz / ((NF / 128) * (CAP / 128));
  int rem = swz % ((NF / 128) * (CAP / 128));
  int bn0 = (rem / (CAP / 128)) * 128;
  int bm0 = (rem % (CAP / 128)) * 128;
  const char* A = (const char*)(Xd + (size_t)e * CAP * ND);
  const char* B = (const char*)(W1t + (size_t)e * NF * ND);
  __shared__ __align__(16) char smem[32768];
  f32x4 zero4 = {0.f, 0.f, 0.f, 0.f};
  f32x4 acc[4][4];
#pragma unroll
  for (int m = 0; m < 4; ++m)
#pragma unroll
    for (int n = 0; n < 4; ++n) acc[m][n] = zero4;
  gemm_mainloop(A, B, 0, ND / 64, (size_t)CAP * 128, (size_t)NF * 128, bm0, bn0, smem, acc);
  const int lane = threadIdx.x & 63, wid = threadIdx.x >> 6;
  const int wr = wid >> 1, wc = wid & 1;
  const int lr = lane & 15, lq = lane >> 4;
  ushort_t* He = H + (size_t)e * CAP * NF;
#pragma unroll
  for (int m = 0; m < 4; ++m) {
#pragma unroll
    for (int n = 0; n < 4; ++n) {
      int col = bn0 + wc * 64 + n * 16 + lr;
      float bias = b1[(size_t)e * NF + col];
      ushort_t* dst = He + (size_t)(col >> 6) * CAP * 64 + (col & 63);
#pragma unroll
      for (int j = 0; j < 4; ++j) {
        int row = bm0 + wr * 64 + m * 16 + lq * 4 + j;
        float v = acc[m][n][j] + bias;
        v = fmaxf(v, 0.f);
        dst[(size_t)row * 64] = f2bf(v);
      }
    }
  }
}

// ---------------- GEMM2 (split-K=2): out[token] += (H_b @ W2t_b^T [+ b2]) * tprob ----------------
// grid 1280; XCD-chunked: 2 (e,s) groups per XCD, n-fastest (8 blocks share an A-panel).
__global__ __launch_bounds__(256) void gemm2_kernel(const ushort_t* __restrict__ H,
                                                    const ushort_t* __restrict__ W2t,
                                                    const float* __restrict__ b2,
                                                    const int* __restrict__ tslot,
                                                    const float* __restrict__ tprob,
                                                    float* __restrict__ out) {
  int swz = xcd_swizzle(blockIdx.x, (ND / 128) * (CAP / 128) * NE * KSPLIT);
  int z = swz / ((ND / 128) * (CAP / 128));
  int rem = swz % ((ND / 128) * (CAP / 128));
  int e = z >> 1, s = z & 1;
  int bm0 = (rem / (ND / 128)) * 128;
  int bn0 = (rem % (ND / 128)) * 128;
  const char* A = (const char*)(H + (size_t)e * CAP * NF);
  const char* B = (const char*)(W2t + (size_t)e * ND * NF);
  __shared__ __align__(16) char smem[32768];
  f32x4 zero4 = {0.f, 0.f, 0.f, 0.f};
  f32x4 acc[4][4];
#pragma unroll
  for (int m = 0; m < 4; ++m)
#pragma unroll
    for (int n = 0; n < 4; ++n) acc[m][n] = zero4;
  const int kbHalf = NF / 64 / KSPLIT;   // 32
  gemm_mainloop(A, B, s * kbHalf, (s + 1) * kbHalf, (size_t)CAP * 128, (size_t)ND * 128,
                bm0, bn0, smem, acc);
  const int lane = threadIdx.x & 63, wid = threadIdx.x >> 6;
  const int wr = wid >> 1, wc = wid & 1;
  const int lr = lane & 15, lq = lane >> 4;
  float bias[4];
#pragma unroll
  for (int n = 0; n < 4; ++n)
    bias[n] = (s == 0) ? b2[(size_t)e * ND + bn0 + wc * 64 + n * 16 + lr] : 0.f;
#pragma unroll
  for (int m = 0; m < 4; ++m) {
#pragma unroll
    for (int j = 0; j < 4; ++j) {
      int row = bm0 + wr * 64 + m * 16 + lq * 4 + j;
      int t = tslot[e * CAP + row];
      if (t >= 0) {
        float p = tprob[t];
#pragma unroll
        for (int n = 0; n < 4; ++n) {
          int col = bn0 + wc * 64 + n * 16 + lr;
          unsafeAtomicAdd(&out[(size_t)t * ND + col], (acc[m][n][j] + bias[n]) * p);
        }
      }
    }
  }
}

extern "C" void kernel_launch(void* const* d_in, const int* in_sizes, int n_in,
                              void* d_out, int out_size, void* d_ws, size_t ws_size,
                              hipStream_t stream) {
  const float* h  = (const float*)d_in[0];
  const float* gw = (const float*)d_in[1];
  const float* gb = (const float*)d_in[2];
  const float* w1 = (const float*)d_in[3];
  const float* b1 = (const float*)d_in[4];
  const float* w2 = (const float*)d_in[5];
  const float* b2 = (const float*)d_in[6];
  float* out = (float*)d_out;
  char* ws = (char*)d_ws;

  ushort_t* W1t = (ushort_t*)(ws + W1T_OFF);
  ushort_t* W2t = (ushort_t*)(ws + W2T_OFF);
  ushort_t* Xd  = (ushort_t*)(ws + XD_OFF);
  ushort_t* H   = (ushort_t*)(ws + H_OFF);
  int* eidx     = (int*)(ws + EIDX_OFF);
  float* tprob  = (float*)(ws + TPROB_OFF);
  int* tslot    = (int*)(ws + TSLOT_OFF);

  zero_kernel<<<1024, 256, 0, stream>>>(out, (long)out_size);
  route_kernel<<<NT / 4, 256, 0, stream>>>(h, gw, gb, eidx, tprob);
  scan_kernel<<<1, 1024, 0, stream>>>(eidx, tslot);
  gather_kernel<<<NE * CAP, 256, 0, stream>>>(h, tslot, Xd);
  transpose_kernel<<<dim3(NF / 64, ND / 64, NE), 256, 0, stream>>>(w1, W1t, ND, NF);
  transpose_kernel<<<dim3(ND / 64, NF / 64, NE), 256, 0, stream>>>(w2, W2t, NF, ND);
  gemm1_kernel<<<(NF / 128) * (CAP / 128) * NE, 256, 0, stream>>>(Xd, W1t, b1, H);
  gemm2_kernel<<<(ND / 128) * (CAP / 128) * NE * KSPLIT, 256, 0, stream>>>(H, W2t, b2, tslot, tprob, out);
}

// Round 9
// 397.805 us; speedup vs baseline: 1.7462x; 1.0371x over previous
//
#include <hip/hip_runtime.h>

typedef unsigned short ushort_t;
typedef __attribute__((ext_vector_type(8))) __bf16 bf16x8;
typedef __attribute__((ext_vector_type(4))) float f32x4;

#define NT 8192     // tokens
#define NE 8        // experts
#define ND 1024     // model dim
#define NF 4096     // ffn dim
#define CAP 1280    // capacity per expert
#define KSPLIT 4    // split-K for GEMM2 (K=1024 per block, symmetric with GEMM1)

// Blocked operand layout (BK=64): per expert, elem (row,k) at [(k>>6)][row][k&63]
// -> one 128-row x 64-k tile = 16KB contiguous.

// ws layout (bytes)
#define W1T_OFF 0u
#define W2T_OFF 67108864u
#define XD_OFF  134217728u
#define H_OFF   155189248u
#define EIDX_OFF 239075328u
#define TPROB_OFF 239108096u
#define TSLOT_OFF 239140864u

__device__ __forceinline__ unsigned short f2bf(float f) {
  unsigned int u = __float_as_uint(f);
  unsigned int r = (u + 0x7fffu + ((u >> 16) & 1u)) >> 16;
  return (unsigned short)r;
}

// bijective XCD-chunked remap (m204): contiguous chunk of tiles per XCD
__device__ __forceinline__ int xcd_swizzle(int wgid, int nwg) {
  int q = nwg >> 3, r = nwg & 7;
  int xcd = wgid & 7, idx = wgid >> 3;
  return (xcd < r ? xcd * (q + 1) : r * (q + 1) + (xcd - r) * q) + idx;
}

// ---------------- routing (one wave per token) + fused out-row zeroing ----------------
__global__ void route_kernel(const float* __restrict__ x, const float* __restrict__ gw,
                             const float* __restrict__ gb, int* __restrict__ eidx,
                             float* __restrict__ tprob, float* __restrict__ out) {
  int wid = threadIdx.x >> 6, lane = threadIdx.x & 63;
  int t = blockIdx.x * 4 + wid;
  // zero this token's output row (dropped tokens must output 0; atomics accumulate)
  {
    float4 z4 = make_float4(0.f, 0.f, 0.f, 0.f);
    float4* orow = (float4*)(out + (size_t)t * ND);
#pragma unroll
    for (int c = 0; c < 4; ++c) orow[lane + c * 64] = z4;
  }
  const float4* xv = (const float4*)(x + (size_t)t * ND);
  float acc[NE];
#pragma unroll
  for (int e = 0; e < NE; ++e) acc[e] = 0.f;
#pragma unroll
  for (int c = 0; c < 4; ++c) {
    float4 xx = xv[lane * 4 + c];
#pragma unroll
    for (int e = 0; e < NE; ++e) {
      float4 wv = *(const float4*)(gw + (size_t)e * ND + lane * 16 + c * 4);
      acc[e] += xx.x * wv.x + xx.y * wv.y + xx.z * wv.z + xx.w * wv.w;
    }
  }
#pragma unroll
  for (int off = 32; off >= 1; off >>= 1) {
#pragma unroll
    for (int e = 0; e < NE; ++e) acc[e] += __shfl_xor(acc[e], off, 64);
  }
  if (lane == 0) {
    float l[NE];
#pragma unroll
    for (int e = 0; e < NE; ++e) l[e] = acc[e] + gb[e];
    float mx = l[0];
    int am = 0;
#pragma unroll
    for (int e = 1; e < NE; ++e) {
      if (l[e] > mx) { mx = l[e]; am = e; }   // first occurrence kept on ties
    }
    float s = 0.f;
#pragma unroll
    for (int e = 0; e < NE; ++e) s += __expf(l[e] - mx);
    eidx[t] = am;
    tprob[t] = 1.0f / s;
  }
}

// ---------------- capacity scan (single block, order-preserving, wave-shuffle) ----------------
__global__ void scan_kernel(const int* __restrict__ eidx, int* __restrict__ tslot) {
  __shared__ unsigned long long w0[16], w1[16];
  int tid = threadIdx.x;
  int lane = tid & 63, wid = tid >> 6;
  for (int i = tid; i < NE * CAP; i += 1024) tslot[i] = -1;
  int myE[8];
  unsigned long long a = 0, b = 0;
#pragma unroll
  for (int i = 0; i < 8; ++i) {
    int e = eidx[tid * 8 + i];
    myE[i] = e;
    if (e < 4) a += 1ULL << (16 * e);
    else       b += 1ULL << (16 * (e - 4));
  }
  unsigned long long ia = a, ib = b;
#pragma unroll
  for (int off = 1; off < 64; off <<= 1) {
    unsigned long long pa = __shfl_up(ia, off, 64);
    unsigned long long pb = __shfl_up(ib, off, 64);
    if (lane >= off) { ia += pa; ib += pb; }
  }
  if (lane == 63) { w0[wid] = ia; w1[wid] = ib; }
  __syncthreads();
  if (wid == 0 && lane < 16) {
    unsigned long long va = w0[lane], vb = w1[lane];
#pragma unroll
    for (int off = 1; off < 16; off <<= 1) {
      unsigned long long pa = __shfl_up(va, off, 64);
      unsigned long long pb = __shfl_up(vb, off, 64);
      if (lane >= off) { va += pa; vb += pb; }
    }
    w0[lane] = va; w1[lane] = vb;
  }
  __syncthreads();
  unsigned long long ea = ia - a, eb = ib - b;
  if (wid > 0) { ea += w0[wid - 1]; eb += w1[wid - 1]; }
  int base[NE];
#pragma unroll
  for (int e = 0; e < 4; ++e) {
    base[e]     = (int)((ea >> (16 * e)) & 0xffffULL);
    base[4 + e] = (int)((eb >> (16 * e)) & 0xffffULL);
  }
#pragma unroll
  for (int i = 0; i < 8; ++i) {
    int t = tid * 8 + i;
    int e = myE[i];
    int p = base[e]++;
    if (p < CAP) tslot[e * CAP + p] = t;
  }
}

// ---------------- gather tokens -> bf16 dispatch buffer (blocked-64) ----------------
__global__ void gather_kernel(const float* __restrict__ x, const int* __restrict__ tslot,
                              ushort_t* __restrict__ Xd) {
  int slot = blockIdx.x;
  int e = slot / CAP, row = slot % CAP;
  int t = tslot[slot];
  int d = threadIdx.x * 4;
  ushort4 u;
  if (t >= 0) {
    float4 v = *(const float4*)(x + (size_t)t * ND + d);
    u.x = f2bf(v.x); u.y = f2bf(v.y); u.z = f2bf(v.z); u.w = f2bf(v.w);
  } else {
    u.x = 0; u.y = 0; u.z = 0; u.w = 0;
  }
  ushort_t* dst = Xd + (size_t)e * CAP * ND + (size_t)(d >> 6) * CAP * 64 + row * 64 + (d & 63);
  *(ushort4*)dst = u;
}

// ---------------- merged transpose+convert: w1 AND w2 in one launch ----------------
// W [E][K][N] fp32 -> Wt_b [E][K/64][N][64] bf16. 1D grid: first half W1, second half W2.
__global__ void transpose_kernel(const float* __restrict__ w1, ushort_t* __restrict__ W1t,
                                 const float* __restrict__ w2, ushort_t* __restrict__ W2t) {
  int bid = blockIdx.x;
  const float* W; ushort_t* Wt; int K, N, e, rem;
  if (bid < 8192) {                 // W1: K=1024 (16 ktiles), N=4096 (64 ntiles)
    W = w1; Wt = W1t; K = ND; N = NF;
    e = bid >> 10; rem = bid & 1023;          // 64n x 16k
  } else {                          // W2: K=4096 (64 ktiles), N=1024 (16 ntiles)
    W = w2; Wt = W2t; K = NF; N = ND;
    int b = bid - 8192;
    e = b >> 10; rem = b & 1023;
  }
  int nt = N >> 6;                  // n-tiles
  int n0 = (rem % nt) << 6, k0 = (rem / nt) << 6;
  __shared__ float tile[64][65];
  const float* We = W + (size_t)e * K * N;
  ushort_t* Wte = Wt + (size_t)e * K * N + (size_t)(k0 >> 6) * N * 64;
  for (int i = threadIdx.x; i < 1024; i += 256) {
    int r = i >> 4, c4 = (i & 15) << 2;
    float4 v = *(const float4*)(We + (size_t)(k0 + r) * N + n0 + c4);
    tile[r][c4] = v.x; tile[r][c4 + 1] = v.y; tile[r][c4 + 2] = v.z; tile[r][c4 + 3] = v.w;
  }
  __syncthreads();
  for (int i = threadIdx.x; i < 512; i += 256) {
    int n = i >> 3, kq = (i & 7) << 3;
    uint4 u;
    u.x = (unsigned)f2bf(tile[kq + 0][n]) | ((unsigned)f2bf(tile[kq + 1][n]) << 16);
    u.y = (unsigned)f2bf(tile[kq + 2][n]) | ((unsigned)f2bf(tile[kq + 3][n]) << 16);
    u.z = (unsigned)f2bf(tile[kq + 4][n]) | ((unsigned)f2bf(tile[kq + 5][n]) << 16);
    u.w = (unsigned)f2bf(tile[kq + 6][n]) | ((unsigned)f2bf(tile[kq + 7][n]) << 16);
    *(uint4*)(Wte + (size_t)(n0 + n) * 64 + kq) = u;
  }
}

// ---------------- GEMM mainloop: 2-phase double-buffered pipeline (R4-verified) ----------------
// STAGE(t+1) issued BEFORE compute(t); single __syncthreads per K-step.
// LDS: 2 buffers x (16KB A + 16KB B), ((row&7)<<4) XOR swizzle via pre-swizzled source.
__device__ __forceinline__ void gemm_mainloop(const char* __restrict__ Ab,
                                              const char* __restrict__ Bb,
                                              int kbStart, int kbEnd,
                                              size_t aBlkB, size_t bBlkB,
                                              int bm0, int bn0, char* smem,
                                              f32x4 acc[4][4]) {
  const int tid = threadIdx.x;
  const int lane = tid & 63, wid = tid >> 6;
  const int wr = wid >> 1, wc = wid & 1;
  const int lr = lane & 15, lq = lane >> 4;

  auto stage = [&](int kb, int buf) {
    const char* bA = Ab + (size_t)kb * aBlkB + (size_t)bm0 * 128;
    const char* bB = Bb + (size_t)kb * bBlkB + (size_t)bn0 * 128;
    char* sA = smem + buf * 32768;
    char* sB = sA + 16384;
#pragma unroll
    for (int r = 0; r < 4; ++r) {
      int o = r * 4096 + tid * 16;
      int row = o >> 7;
      int src = (o & ~127) | ((o & 127) ^ ((row & 7) << 4));
      __builtin_amdgcn_global_load_lds((const __attribute__((address_space(1))) void*)(bA + src),
                                       (__attribute__((address_space(3))) void*)(sA + o),
                                       16, 0, 0);
      __builtin_amdgcn_global_load_lds((const __attribute__((address_space(1))) void*)(bB + src),
                                       (__attribute__((address_space(3))) void*)(sB + o),
                                       16, 0, 0);
    }
  };

  stage(kbStart, 0);
  __syncthreads();
  int cur = 0;
  for (int kb = kbStart; kb < kbEnd; ++kb) {
    if (kb + 1 < kbEnd) stage(kb + 1, cur ^ 1);   // prefetch overlaps compute below
    char* sA = smem + cur * 32768;
    char* sB = sA + 16384;
    __builtin_amdgcn_s_setprio(1);
#pragma unroll
    for (int kk = 0; kk < 2; ++kk) {
      const int kbyte = kk * 64 + lq * 16;
      bf16x8 av[4], bv[4];
#pragma unroll
      for (int m = 0; m < 4; ++m) {
        int row = wr * 64 + m * 16 + lr;
        int off = ((row << 7) + kbyte) ^ ((lr & 7) << 4);
        av[m] = *(const bf16x8*)(sA + off);
      }
#pragma unroll
      for (int n = 0; n < 4; ++n) {
        int row = wc * 64 + n * 16 + lr;
        int off = ((row << 7) + kbyte) ^ ((lr & 7) << 4);
        bv[n] = *(const bf16x8*)(sB + off);
      }
#pragma unroll
      for (int m = 0; m < 4; ++m)
#pragma unroll
        for (int n = 0; n < 4; ++n)
          acc[m][n] = __builtin_amdgcn_mfma_f32_16x16x32_bf16(av[m], bv[n], acc[m][n], 0, 0, 0);
    }
    __builtin_amdgcn_s_setprio(0);
    __syncthreads();
    cur ^= 1;
  }
}

// ---------------- GEMM1: H_b = relu(Xd_b @ W1t_b^T + b1), bf16 blocked out ----------------
// grid 2560; XCD-chunked: one expert per XCD, m-fastest (10 blocks share a B-panel).
__global__ __launch_bounds__(256) void gemm1_kernel(const ushort_t* __restrict__ Xd,
                                                    const ushort_t* __restrict__ W1t,
                                                    const float* __restrict__ b1,
                                                    ushort_t* __restrict__ H) {
  int swz = xcd_swizzle(blockIdx.x, (NF / 128) * (CAP / 128) * NE);
  int e = swz / ((NF / 128) * (CAP / 128));
  int rem = swz % ((NF / 128) * (CAP / 128));
  int bn0 = (rem / (CAP / 128)) * 128;
  int bm0 = (rem % (CAP / 128)) * 128;
  const char* A = (const char*)(Xd + (size_t)e * CAP * ND);
  const char* B = (const char*)(W1t + (size_t)e * NF * ND);
  __shared__ __align__(16) char smem[65536];
  f32x4 zero4 = {0.f, 0.f, 0.f, 0.f};
  f32x4 acc[4][4];
#pragma unroll
  for (int m = 0; m < 4; ++m)
#pragma unroll
    for (int n = 0; n < 4; ++n) acc[m][n] = zero4;
  gemm_mainloop(A, B, 0, ND / 64, (size_t)CAP * 128, (size_t)NF * 128, bm0, bn0, smem, acc);
  const int lane = threadIdx.x & 63, wid = threadIdx.x >> 6;
  const int wr = wid >> 1, wc = wid & 1;
  const int lr = lane & 15, lq = lane >> 4;
  ushort_t* He = H + (size_t)e * CAP * NF;
#pragma unroll
  for (int m = 0; m < 4; ++m) {
#pragma unroll
    for (int n = 0; n < 4; ++n) {
      int col = bn0 + wc * 64 + n * 16 + lr;
      float bias = b1[(size_t)e * NF + col];
      ushort_t* dst = He + (size_t)(col >> 6) * CAP * 64 + (col & 63);
#pragma unroll
      for (int j = 0; j < 4; ++j) {
        int row = bm0 + wr * 64 + m * 16 + lq * 4 + j;
        float v = acc[m][n][j] + bias;
        v = fmaxf(v, 0.f);
        dst[(size_t)row * 64] = f2bf(v);
      }
    }
  }
}

// ---------------- GEMM2 (split-K=4): out[token] += (H_b @ W2t_b^T [+ b2]) * tprob ----------------
// grid 2560; XCD-chunked: one expert per XCD (e = z>>2), 4 split groups of 80; n-fastest.
__global__ __launch_bounds__(256) void gemm2_kernel(const ushort_t* __restrict__ H,
                                                    const ushort_t* __restrict__ W2t,
                                                    const float* __restrict__ b2,
                                                    const int* __restrict__ tslot,
                                                    const float* __restrict__ tprob,
                                                    float* __restrict__ out) {
  int swz = xcd_swizzle(blockIdx.x, (ND / 128) * (CAP / 128) * NE * KSPLIT);
  int z = swz / ((ND / 128) * (CAP / 128));        // 0..31 = xcd*4 + group
  int rem = swz % ((ND / 128) * (CAP / 128));
  int e = z >> 2, s = z & 3;
  int bm0 = (rem / (ND / 128)) * 128;
  int bn0 = (rem % (ND / 128)) * 128;
  const char* A = (const char*)(H + (size_t)e * CAP * NF);
  const char* B = (const char*)(W2t + (size_t)e * ND * NF);
  __shared__ __align__(16) char smem[65536];
  f32x4 zero4 = {0.f, 0.f, 0.f, 0.f};
  f32x4 acc[4][4];
#pragma unroll
  for (int m = 0; m < 4; ++m)
#pragma unroll
    for (int n = 0; n < 4; ++n) acc[m][n] = zero4;
  const int kbQ = NF / 64 / KSPLIT;   // 16
  gemm_mainloop(A, B, s * kbQ, (s + 1) * kbQ, (size_t)CAP * 128, (size_t)ND * 128,
                bm0, bn0, smem, acc);
  const int lane = threadIdx.x & 63, wid = threadIdx.x >> 6;
  const int wr = wid >> 1, wc = wid & 1;
  const int lr = lane & 15, lq = lane >> 4;
  float bias[4];
#pragma unroll
  for (int n = 0; n < 4; ++n)
    bias[n] = (s == 0) ? b2[(size_t)e * ND + bn0 + wc * 64 + n * 16 + lr] : 0.f;
#pragma unroll
  for (int m = 0; m < 4; ++m) {
#pragma unroll
    for (int j = 0; j < 4; ++j) {
      int row = bm0 + wr * 64 + m * 16 + lq * 4 + j;
      int t = tslot[e * CAP + row];
      if (t >= 0) {
        float p = tprob[t];
#pragma unroll
        for (int n = 0; n < 4; ++n) {
          int col = bn0 + wc * 64 + n * 16 + lr;
          unsafeAtomicAdd(&out[(size_t)t * ND + col], (acc[m][n][j] + bias[n]) * p);
        }
      }
    }
  }
}

extern "C" void kernel_launch(void* const* d_in, const int* in_sizes, int n_in,
                              void* d_out, int out_size, void* d_ws, size_t ws_size,
                              hipStream_t stream) {
  const float* h  = (const float*)d_in[0];
  const float* gw = (const float*)d_in[1];
  const float* gb = (const float*)d_in[2];
  const float* w1 = (const float*)d_in[3];
  const float* b1 = (const float*)d_in[4];
  const float* w2 = (const float*)d_in[5];
  const float* b2 = (const float*)d_in[6];
  float* out = (float*)d_out;
  char* ws = (char*)d_ws;

  ushort_t* W1t = (ushort_t*)(ws + W1T_OFF);
  ushort_t* W2t = (ushort_t*)(ws + W2T_OFF);
  ushort_t* Xd  = (ushort_t*)(ws + XD_OFF);
  ushort_t* H   = (ushort_t*)(ws + H_OFF);
  int* eidx     = (int*)(ws + EIDX_OFF);
  float* tprob  = (float*)(ws + TPROB_OFF);
  int* tslot    = (int*)(ws + TSLOT_OFF);

  route_kernel<<<NT / 4, 256, 0, stream>>>(h, gw, gb, eidx, tprob, out);
  scan_kernel<<<1, 1024, 0, stream>>>(eidx, tslot);
  gather_kernel<<<NE * CAP, 256, 0, stream>>>(h, tslot, Xd);
  transpose_kernel<<<16384, 256, 0, stream>>>(w1, W1t, w2, W2t);
  gemm1_kernel<<<(NF / 128) * (CAP / 128) * NE, 256, 0, stream>>>(Xd, W1t, b1, H);
  gemm2_kernel<<<(ND / 128) * (CAP / 128) * NE * KSPLIT, 256, 0, stream>>>(H, W2t, b2, tslot, tprob, out);
}

// Round 10
// 366.155 us; speedup vs baseline: 1.8971x; 1.0864x over previous
//
#include <hip/hip_runtime.h>

typedef unsigned short ushort_t;
typedef __attribute__((ext_vector_type(8))) __bf16 bf16x8;
typedef __attribute__((ext_vector_type(4))) float f32x4;

#define NT 8192     // tokens
#define NE 8        // experts
#define ND 1024     // model dim
#define NF 4096     // ffn dim
#define CAP 1280    // capacity per expert
#define KSPLIT 2    // split-K for GEMM2 (R4-verified best: 149us)

// Blocked operand layout (BK=64): per expert, elem (row,k) at [(k>>6)][row][k&63]
// -> one 128-row x 64-k tile = 16KB contiguous.

// ws layout (bytes)
#define W1T_OFF 0u
#define W2T_OFF 67108864u
#define XD_OFF  134217728u
#define H_OFF   155189248u
#define EIDX_OFF 239075328u
#define TPROB_OFF 239108096u
#define TSLOT_OFF 239140864u

__device__ __forceinline__ unsigned short f2bf(float f) {
  unsigned int u = __float_as_uint(f);
  unsigned int r = (u + 0x7fffu + ((u >> 16) & 1u)) >> 16;
  return (unsigned short)r;
}

// bijective XCD-chunked remap (m204): contiguous chunk of tiles per XCD
__device__ __forceinline__ int xcd_swizzle(int wgid, int nwg) {
  int q = nwg >> 3, r = nwg & 7;
  int xcd = wgid & 7, idx = wgid >> 3;
  return (xcd < r ? xcd * (q + 1) : r * (q + 1) + (xcd - r) * q) + idx;
}

// ---------------- routing (one wave per token) + fused out-row zeroing ----------------
__global__ void route_kernel(const float* __restrict__ x, const float* __restrict__ gw,
                             const float* __restrict__ gb, int* __restrict__ eidx,
                             float* __restrict__ tprob, float* __restrict__ out) {
  int wid = threadIdx.x >> 6, lane = threadIdx.x & 63;
  int t = blockIdx.x * 4 + wid;
  // zero this token's output row (dropped tokens must output 0; atomics accumulate)
  {
    float4 z4 = make_float4(0.f, 0.f, 0.f, 0.f);
    float4* orow = (float4*)(out + (size_t)t * ND);
#pragma unroll
    for (int c = 0; c < 4; ++c) orow[lane + c * 64] = z4;
  }
  const float4* xv = (const float4*)(x + (size_t)t * ND);
  float acc[NE];
#pragma unroll
  for (int e = 0; e < NE; ++e) acc[e] = 0.f;
#pragma unroll
  for (int c = 0; c < 4; ++c) {
    float4 xx = xv[lane * 4 + c];
#pragma unroll
    for (int e = 0; e < NE; ++e) {
      float4 wv = *(const float4*)(gw + (size_t)e * ND + lane * 16 + c * 4);
      acc[e] += xx.x * wv.x + xx.y * wv.y + xx.z * wv.z + xx.w * wv.w;
    }
  }
#pragma unroll
  for (int off = 32; off >= 1; off >>= 1) {
#pragma unroll
    for (int e = 0; e < NE; ++e) acc[e] += __shfl_xor(acc[e], off, 64);
  }
  if (lane == 0) {
    float l[NE];
#pragma unroll
    for (int e = 0; e < NE; ++e) l[e] = acc[e] + gb[e];
    float mx = l[0];
    int am = 0;
#pragma unroll
    for (int e = 1; e < NE; ++e) {
      if (l[e] > mx) { mx = l[e]; am = e; }   // first occurrence kept on ties
    }
    float s = 0.f;
#pragma unroll
    for (int e = 0; e < NE; ++e) s += __expf(l[e] - mx);
    eidx[t] = am;
    tprob[t] = 1.0f / s;
  }
}

// ---------------- capacity scan (single block, order-preserving, wave-shuffle) ----------------
__global__ void scan_kernel(const int* __restrict__ eidx, int* __restrict__ tslot) {
  __shared__ unsigned long long w0[16], w1[16];
  int tid = threadIdx.x;
  int lane = tid & 63, wid = tid >> 6;
  for (int i = tid; i < NE * CAP; i += 1024) tslot[i] = -1;
  int myE[8];
  unsigned long long a = 0, b = 0;
#pragma unroll
  for (int i = 0; i < 8; ++i) {
    int e = eidx[tid * 8 + i];
    myE[i] = e;
    if (e < 4) a += 1ULL << (16 * e);
    else       b += 1ULL << (16 * (e - 4));
  }
  unsigned long long ia = a, ib = b;
#pragma unroll
  for (int off = 1; off < 64; off <<= 1) {
    unsigned long long pa = __shfl_up(ia, off, 64);
    unsigned long long pb = __shfl_up(ib, off, 64);
    if (lane >= off) { ia += pa; ib += pb; }
  }
  if (lane == 63) { w0[wid] = ia; w1[wid] = ib; }
  __syncthreads();
  if (wid == 0 && lane < 16) {
    unsigned long long va = w0[lane], vb = w1[lane];
#pragma unroll
    for (int off = 1; off < 16; off <<= 1) {
      unsigned long long pa = __shfl_up(va, off, 64);
      unsigned long long pb = __shfl_up(vb, off, 64);
      if (lane >= off) { va += pa; vb += pb; }
    }
    w0[lane] = va; w1[lane] = vb;
  }
  __syncthreads();
  unsigned long long ea = ia - a, eb = ib - b;
  if (wid > 0) { ea += w0[wid - 1]; eb += w1[wid - 1]; }
  int base[NE];
#pragma unroll
  for (int e = 0; e < 4; ++e) {
    base[e]     = (int)((ea >> (16 * e)) & 0xffffULL);
    base[4 + e] = (int)((eb >> (16 * e)) & 0xffffULL);
  }
#pragma unroll
  for (int i = 0; i < 8; ++i) {
    int t = tid * 8 + i;
    int e = myE[i];
    int p = base[e]++;
    if (p < CAP) tslot[e * CAP + p] = t;
  }
}

// ---------------- gather tokens -> bf16 dispatch buffer (blocked-64) ----------------
__global__ void gather_kernel(const float* __restrict__ x, const int* __restrict__ tslot,
                              ushort_t* __restrict__ Xd) {
  int slot = blockIdx.x;
  int e = slot / CAP, row = slot % CAP;
  int t = tslot[slot];
  int d = threadIdx.x * 4;
  ushort4 u;
  if (t >= 0) {
    float4 v = *(const float4*)(x + (size_t)t * ND + d);
    u.x = f2bf(v.x); u.y = f2bf(v.y); u.z = f2bf(v.z); u.w = f2bf(v.w);
  } else {
    u.x = 0; u.y = 0; u.z = 0; u.w = 0;
  }
  ushort_t* dst = Xd + (size_t)e * CAP * ND + (size_t)(d >> 6) * CAP * 64 + row * 64 + (d & 63);
  *(ushort4*)dst = u;
}

// ---------------- merged transpose+convert: w1 AND w2 in one launch ----------------
// W [E][K][N] fp32 -> Wt_b [E][K/64][N][64] bf16. 1D grid: first half W1, second half W2.
__global__ void transpose_kernel(const float* __restrict__ w1, ushort_t* __restrict__ W1t,
                                 const float* __restrict__ w2, ushort_t* __restrict__ W2t) {
  int bid = blockIdx.x;
  const float* W; ushort_t* Wt; int K, N, e, rem;
  if (bid < 8192) {                 // W1: K=1024 (16 ktiles), N=4096 (64 ntiles)
    W = w1; Wt = W1t; K = ND; N = NF;
    e = bid >> 10; rem = bid & 1023;
  } else {                          // W2: K=4096 (64 ktiles), N=1024 (16 ntiles)
    W = w2; Wt = W2t; K = NF; N = ND;
    int b = bid - 8192;
    e = b >> 10; rem = b & 1023;
  }
  int nt = N >> 6;                  // n-tiles
  int n0 = (rem % nt) << 6, k0 = (rem / nt) << 6;
  __shared__ float tile[64][65];
  const float* We = W + (size_t)e * K * N;
  ushort_t* Wte = Wt + (size_t)e * K * N + (size_t)(k0 >> 6) * N * 64;
  for (int i = threadIdx.x; i < 1024; i += 256) {
    int r = i >> 4, c4 = (i & 15) << 2;
    float4 v = *(const float4*)(We + (size_t)(k0 + r) * N + n0 + c4);
    tile[r][c4] = v.x; tile[r][c4 + 1] = v.y; tile[r][c4 + 2] = v.z; tile[r][c4 + 3] = v.w;
  }
  __syncthreads();
  for (int i = threadIdx.x; i < 512; i += 256) {
    int n = i >> 3, kq = (i & 7) << 3;
    uint4 u;
    u.x = (unsigned)f2bf(tile[kq + 0][n]) | ((unsigned)f2bf(tile[kq + 1][n]) << 16);
    u.y = (unsigned)f2bf(tile[kq + 2][n]) | ((unsigned)f2bf(tile[kq + 3][n]) << 16);
    u.z = (unsigned)f2bf(tile[kq + 4][n]) | ((unsigned)f2bf(tile[kq + 5][n]) << 16);
    u.w = (unsigned)f2bf(tile[kq + 6][n]) | ((unsigned)f2bf(tile[kq + 7][n]) << 16);
    *(uint4*)(Wte + (size_t)(n0 + n) * 64 + kq) = u;
  }
}

// ---------------- GEMM mainloop: 2-phase double-buffered pipeline (R4-verified) ----------------
// STAGE(t+1) issued BEFORE compute(t); single __syncthreads per K-step.
// LDS: 2 buffers x (16KB A + 16KB B), ((row&7)<<4) XOR swizzle via pre-swizzled source.
__device__ __forceinline__ void gemm_mainloop(const char* __restrict__ Ab,
                                              const char* __restrict__ Bb,
                                              int kbStart, int kbEnd,
                                              size_t aBlkB, size_t bBlkB,
                                              int bm0, int bn0, char* smem,
                                              f32x4 acc[4][4]) {
  const int tid = threadIdx.x;
  const int lane = tid & 63, wid = tid >> 6;
  const int wr = wid >> 1, wc = wid & 1;
  const int lr = lane & 15, lq = lane >> 4;

  auto stage = [&](int kb, int buf) {
    const char* bA = Ab + (size_t)kb * aBlkB + (size_t)bm0 * 128;
    const char* bB = Bb + (size_t)kb * bBlkB + (size_t)bn0 * 128;
    char* sA = smem + buf * 32768;
    char* sB = sA + 16384;
#pragma unroll
    for (int r = 0; r < 4; ++r) {
      int o = r * 4096 + tid * 16;
      int row = o >> 7;
      int src = (o & ~127) | ((o & 127) ^ ((row & 7) << 4));
      __builtin_amdgcn_global_load_lds((const __attribute__((address_space(1))) void*)(bA + src),
                                       (__attribute__((address_space(3))) void*)(sA + o),
                                       16, 0, 0);
      __builtin_amdgcn_global_load_lds((const __attribute__((address_space(1))) void*)(bB + src),
                                       (__attribute__((address_space(3))) void*)(sB + o),
                                       16, 0, 0);
    }
  };

  stage(kbStart, 0);
  __syncthreads();
  int cur = 0;
  for (int kb = kbStart; kb < kbEnd; ++kb) {
    if (kb + 1 < kbEnd) stage(kb + 1, cur ^ 1);   // prefetch overlaps compute below
    char* sA = smem + cur * 32768;
    char* sB = sA + 16384;
    __builtin_amdgcn_s_setprio(1);
#pragma unroll
    for (int kk = 0; kk < 2; ++kk) {
      const int kbyte = kk * 64 + lq * 16;
      bf16x8 av[4], bv[4];
#pragma unroll
      for (int m = 0; m < 4; ++m) {
        int row = wr * 64 + m * 16 + lr;
        int off = ((row << 7) + kbyte) ^ ((lr & 7) << 4);
        av[m] = *(const bf16x8*)(sA + off);
      }
#pragma unroll
      for (int n = 0; n < 4; ++n) {
        int row = wc * 64 + n * 16 + lr;
        int off = ((row << 7) + kbyte) ^ ((lr & 7) << 4);
        bv[n] = *(const bf16x8*)(sB + off);
      }
#pragma unroll
      for (int m = 0; m < 4; ++m)
#pragma unroll
        for (int n = 0; n < 4; ++n)
          acc[m][n] = __builtin_amdgcn_mfma_f32_16x16x32_bf16(av[m], bv[n], acc[m][n], 0, 0, 0);
    }
    __builtin_amdgcn_s_setprio(0);
    __syncthreads();
    cur ^= 1;
  }
}

// ---------------- GEMM1: H_b = relu(Xd_b @ W1t_b^T + b1), bf16 blocked out ----------------
// grid 2560; XCD-chunked: one expert per XCD, m-fastest (10 blocks share a B-panel).
__global__ __launch_bounds__(256) void gemm1_kernel(const ushort_t* __restrict__ Xd,
                                                    const ushort_t* __restrict__ W1t,
                                                    const float* __restrict__ b1,
                                                    ushort_t* __restrict__ H) {
  int swz = xcd_swizzle(blockIdx.x, (NF / 128) * (CAP / 128) * NE);
  int e = swz / ((NF / 128) * (CAP / 128));
  int rem = swz % ((NF / 128) * (CAP / 128));
  int bn0 = (rem / (CAP / 128)) * 128;
  int bm0 = (rem % (CAP / 128)) * 128;
  const char* A = (const char*)(Xd + (size_t)e * CAP * ND);
  const char* B = (const char*)(W1t + (size_t)e * NF * ND);
  __shared__ __align__(16) char smem[65536];
  f32x4 zero4 = {0.f, 0.f, 0.f, 0.f};
  f32x4 acc[4][4];
#pragma unroll
  for (int m = 0; m < 4; ++m)
#pragma unroll
    for (int n = 0; n < 4; ++n) acc[m][n] = zero4;
  gemm_mainloop(A, B, 0, ND / 64, (size_t)CAP * 128, (size_t)NF * 128, bm0, bn0, smem, acc);
  const int lane = threadIdx.x & 63, wid = threadIdx.x >> 6;
  const int wr = wid >> 1, wc = wid & 1;
  const int lr = lane & 15, lq = lane >> 4;
  ushort_t* He = H + (size_t)e * CAP * NF;
#pragma unroll
  for (int m = 0; m < 4; ++m) {
#pragma unroll
    for (int n = 0; n < 4; ++n) {
      int col = bn0 + wc * 64 + n * 16 + lr;
      float bias = b1[(size_t)e * NF + col];
      ushort_t* dst = He + (size_t)(col >> 6) * CAP * 64 + (col & 63);
#pragma unroll
      for (int j = 0; j < 4; ++j) {
        int row = bm0 + wr * 64 + m * 16 + lq * 4 + j;
        float v = acc[m][n][j] + bias;
        v = fmaxf(v, 0.f);
        dst[(size_t)row * 64] = f2bf(v);
      }
    }
  }
}

// ---------------- GEMM2 (split-K=2): out[token] += (H_b @ W2t_b^T [+ b2]) * tprob ----------------
// grid 1280; XCD-chunked: 2 (e,s) groups per XCD, n-fastest (8 blocks share an A-panel).
// R4-verified config: 149us.
__global__ __launch_bounds__(256) void gemm2_kernel(const ushort_t* __restrict__ H,
                                                    const ushort_t* __restrict__ W2t,
                                                    const float* __restrict__ b2,
                                                    const int* __restrict__ tslot,
                                                    const float* __restrict__ tprob,
                                                    float* __restrict__ out) {
  int swz = xcd_swizzle(blockIdx.x, (ND / 128) * (CAP / 128) * NE * KSPLIT);
  int z = swz / ((ND / 128) * (CAP / 128));
  int rem = swz % ((ND / 128) * (CAP / 128));
  int e = z >> 1, s = z & 1;
  int bm0 = (rem / (ND / 128)) * 128;
  int bn0 = (rem % (ND / 128)) * 128;
  const char* A = (const char*)(H + (size_t)e * CAP * NF);
  const char* B = (const char*)(W2t + (size_t)e * ND * NF);
  __shared__ __align__(16) char smem[65536];
  f32x4 zero4 = {0.f, 0.f, 0.f, 0.f};
  f32x4 acc[4][4];
#pragma unroll
  for (int m = 0; m < 4; ++m)
#pragma unroll
    for (int n = 0; n < 4; ++n) acc[m][n] = zero4;
  const int kbHalf = NF / 64 / KSPLIT;   // 32
  gemm_mainloop(A, B, s * kbHalf, (s + 1) * kbHalf, (size_t)CAP * 128, (size_t)ND * 128,
                bm0, bn0, smem, acc);
  const int lane = threadIdx.x & 63, wid = threadIdx.x >> 6;
  const int wr = wid >> 1, wc = wid & 1;
  const int lr = lane & 15, lq = lane >> 4;
  float bias[4];
#pragma unroll
  for (int n = 0; n < 4; ++n)
    bias[n] = (s == 0) ? b2[(size_t)e * ND + bn0 + wc * 64 + n * 16 + lr] : 0.f;
#pragma unroll
  for (int m = 0; m < 4; ++m) {
#pragma unroll
    for (int j = 0; j < 4; ++j) {
      int row = bm0 + wr * 64 + m * 16 + lq * 4 + j;
      int t = tslot[e * CAP + row];
      if (t >= 0) {
        float p = tprob[t];
#pragma unroll
        for (int n = 0; n < 4; ++n) {
          int col = bn0 + wc * 64 + n * 16 + lr;
          unsafeAtomicAdd(&out[(size_t)t * ND + col], (acc[m][n][j] + bias[n]) * p);
        }
      }
    }
  }
}

extern "C" void kernel_launch(void* const* d_in, const int* in_sizes, int n_in,
                              void* d_out, int out_size, void* d_ws, size_t ws_size,
                              hipStream_t stream) {
  const float* h  = (const float*)d_in[0];
  const float* gw = (const float*)d_in[1];
  const float* gb = (const float*)d_in[2];
  const float* w1 = (const float*)d_in[3];
  const float* b1 = (const float*)d_in[4];
  const float* w2 = (const float*)d_in[5];
  const float* b2 = (const float*)d_in[6];
  float* out = (float*)d_out;
  char* ws = (char*)d_ws;

  ushort_t* W1t = (ushort_t*)(ws + W1T_OFF);
  ushort_t* W2t = (ushort_t*)(ws + W2T_OFF);
  ushort_t* Xd  = (ushort_t*)(ws + XD_OFF);
  ushort_t* H   = (ushort_t*)(ws + H_OFF);
  int* eidx     = (int*)(ws + EIDX_OFF);
  float* tprob  = (float*)(ws + TPROB_OFF);
  int* tslot    = (int*)(ws + TSLOT_OFF);

  route_kernel<<<NT / 4, 256, 0, stream>>>(h, gw, gb, eidx, tprob, out);
  scan_kernel<<<1, 1024, 0, stream>>>(eidx, tslot);
  gather_kernel<<<NE * CAP, 256, 0, stream>>>(h, tslot, Xd);
  transpose_kernel<<<16384, 256, 0, stream>>>(w1, W1t, w2, W2t);
  gemm1_kernel<<<(NF / 128) * (CAP / 128) * NE, 256, 0, stream>>>(Xd, W1t, b1, H);
  gemm2_kernel<<<(ND / 128) * (CAP / 128) * NE * KSPLIT, 256, 0, stream>>>(H, W2t, b2, tslot, tprob, out);
}

// Round 11
// 366.120 us; speedup vs baseline: 1.8973x; 1.0001x over previous
//
#include <hip/hip_runtime.h>

typedef unsigned short ushort_t;
typedef __attribute__((ext_vector_type(8))) __bf16 bf16x8;
typedef __attribute__((ext_vector_type(4))) float f32x4;

#define NT 8192     // tokens
#define NE 8        // experts
#define ND 1024     // model dim
#define NF 4096     // ffn dim
#define CAP 1280    // capacity per expert
#define KSPLIT 2    // split-K for GEMM2 (R4/R10-verified best)

// Blocked operand layout (BK=64): per expert, elem (row,k) at [(k>>6)][row][k&63]
// -> one 128-row x 64-k tile = 16KB contiguous.

// ws layout (bytes)
#define W1T_OFF 0u
#define W2T_OFF 67108864u
#define XD_OFF  134217728u
#define H_OFF   155189248u
#define EIDX_OFF 239075328u
#define TPROB_OFF 239108096u
#define TSLOT_OFF 239140864u

__device__ __forceinline__ unsigned short f2bf(float f) {
  unsigned int u = __float_as_uint(f);
  unsigned int r = (u + 0x7fffu + ((u >> 16) & 1u)) >> 16;
  return (unsigned short)r;
}

// bijective XCD-chunked remap (m204): contiguous chunk of tiles per XCD
__device__ __forceinline__ int xcd_swizzle(int wgid, int nwg) {
  int q = nwg >> 3, r = nwg & 7;
  int xcd = wgid & 7, idx = wgid >> 3;
  return (xcd < r ? xcd * (q + 1) : r * (q + 1) + (xcd - r) * q) + idx;
}

// ---------------- routing (one wave per token) + fused out-row zeroing ----------------
__global__ void route_kernel(const float* __restrict__ x, const float* __restrict__ gw,
                             const float* __restrict__ gb, int* __restrict__ eidx,
                             float* __restrict__ tprob, float* __restrict__ out) {
  int wid = threadIdx.x >> 6, lane = threadIdx.x & 63;
  int t = blockIdx.x * 4 + wid;
  // zero this token's output row (dropped tokens must output 0; atomics accumulate)
  {
    float4 z4 = make_float4(0.f, 0.f, 0.f, 0.f);
    float4* orow = (float4*)(out + (size_t)t * ND);
#pragma unroll
    for (int c = 0; c < 4; ++c) orow[lane + c * 64] = z4;
  }
  const float4* xv = (const float4*)(x + (size_t)t * ND);
  float acc[NE];
#pragma unroll
  for (int e = 0; e < NE; ++e) acc[e] = 0.f;
#pragma unroll
  for (int c = 0; c < 4; ++c) {
    float4 xx = xv[lane * 4 + c];
#pragma unroll
    for (int e = 0; e < NE; ++e) {
      float4 wv = *(const float4*)(gw + (size_t)e * ND + lane * 16 + c * 4);
      acc[e] += xx.x * wv.x + xx.y * wv.y + xx.z * wv.z + xx.w * wv.w;
    }
  }
#pragma unroll
  for (int off = 32; off >= 1; off >>= 1) {
#pragma unroll
    for (int e = 0; e < NE; ++e) acc[e] += __shfl_xor(acc[e], off, 64);
  }
  if (lane == 0) {
    float l[NE];
#pragma unroll
    for (int e = 0; e < NE; ++e) l[e] = acc[e] + gb[e];
    float mx = l[0];
    int am = 0;
#pragma unroll
    for (int e = 1; e < NE; ++e) {
      if (l[e] > mx) { mx = l[e]; am = e; }   // first occurrence kept on ties
    }
    float s = 0.f;
#pragma unroll
    for (int e = 0; e < NE; ++e) s += __expf(l[e] - mx);
    eidx[t] = am;
    tprob[t] = 1.0f / s;
  }
}

// ---------------- capacity scan (single block, order-preserving, wave-shuffle) ----------------
__global__ void scan_kernel(const int* __restrict__ eidx, int* __restrict__ tslot) {
  __shared__ unsigned long long w0[16], w1[16];
  int tid = threadIdx.x;
  int lane = tid & 63, wid = tid >> 6;
  for (int i = tid; i < NE * CAP; i += 1024) tslot[i] = -1;
  int myE[8];
  unsigned long long a = 0, b = 0;
#pragma unroll
  for (int i = 0; i < 8; ++i) {
    int e = eidx[tid * 8 + i];
    myE[i] = e;
    if (e < 4) a += 1ULL << (16 * e);
    else       b += 1ULL << (16 * (e - 4));
  }
  unsigned long long ia = a, ib = b;
#pragma unroll
  for (int off = 1; off < 64; off <<= 1) {
    unsigned long long pa = __shfl_up(ia, off, 64);
    unsigned long long pb = __shfl_up(ib, off, 64);
    if (lane >= off) { ia += pa; ib += pb; }
  }
  if (lane == 63) { w0[wid] = ia; w1[wid] = ib; }
  __syncthreads();
  if (wid == 0 && lane < 16) {
    unsigned long long va = w0[lane], vb = w1[lane];
#pragma unroll
    for (int off = 1; off < 16; off <<= 1) {
      unsigned long long pa = __shfl_up(va, off, 64);
      unsigned long long pb = __shfl_up(vb, off, 64);
      if (lane >= off) { va += pa; vb += pb; }
    }
    w0[lane] = va; w1[lane] = vb;
  }
  __syncthreads();
  unsigned long long ea = ia - a, eb = ib - b;
  if (wid > 0) { ea += w0[wid - 1]; eb += w1[wid - 1]; }
  int base[NE];
#pragma unroll
  for (int e = 0; e < 4; ++e) {
    base[e]     = (int)((ea >> (16 * e)) & 0xffffULL);
    base[4 + e] = (int)((eb >> (16 * e)) & 0xffffULL);
  }
#pragma unroll
  for (int i = 0; i < 8; ++i) {
    int t = tid * 8 + i;
    int e = myE[i];
    int p = base[e]++;
    if (p < CAP) tslot[e * CAP + p] = t;
  }
}

// ---------------- gather tokens -> bf16 dispatch buffer (blocked-64) ----------------
__global__ void gather_kernel(const float* __restrict__ x, const int* __restrict__ tslot,
                              ushort_t* __restrict__ Xd) {
  int slot = blockIdx.x;
  int e = slot / CAP, row = slot % CAP;
  int t = tslot[slot];
  int d = threadIdx.x * 4;
  ushort4 u;
  if (t >= 0) {
    float4 v = *(const float4*)(x + (size_t)t * ND + d);
    u.x = f2bf(v.x); u.y = f2bf(v.y); u.z = f2bf(v.z); u.w = f2bf(v.w);
  } else {
    u.x = 0; u.y = 0; u.z = 0; u.w = 0;
  }
  ushort_t* dst = Xd + (size_t)e * CAP * ND + (size_t)(d >> 6) * CAP * 64 + row * 64 + (d & 63);
  *(ushort4*)dst = u;
}

// ---------------- merged transpose+convert: w1 AND w2 in one launch ----------------
// W [E][K][N] fp32 -> Wt_b [E][K/64][N][64] bf16. 1D grid: first half W1, second half W2.
__global__ void transpose_kernel(const float* __restrict__ w1, ushort_t* __restrict__ W1t,
                                 const float* __restrict__ w2, ushort_t* __restrict__ W2t) {
  int bid = blockIdx.x;
  const float* W; ushort_t* Wt; int K, N, e, rem;
  if (bid < 8192) {                 // W1: K=1024 (16 ktiles), N=4096 (64 ntiles)
    W = w1; Wt = W1t; K = ND; N = NF;
    e = bid >> 10; rem = bid & 1023;
  } else {                          // W2: K=4096 (64 ktiles), N=1024 (16 ntiles)
    W = w2; Wt = W2t; K = NF; N = ND;
    int b = bid - 8192;
    e = b >> 10; rem = b & 1023;
  }
  int nt = N >> 6;                  // n-tiles
  int n0 = (rem % nt) << 6, k0 = (rem / nt) << 6;
  __shared__ float tile[64][65];
  const float* We = W + (size_t)e * K * N;
  ushort_t* Wte = Wt + (size_t)e * K * N + (size_t)(k0 >> 6) * N * 64;
  for (int i = threadIdx.x; i < 1024; i += 256) {
    int r = i >> 4, c4 = (i & 15) << 2;
    float4 v = *(const float4*)(We + (size_t)(k0 + r) * N + n0 + c4);
    tile[r][c4] = v.x; tile[r][c4 + 1] = v.y; tile[r][c4 + 2] = v.z; tile[r][c4 + 3] = v.w;
  }
  __syncthreads();
  for (int i = threadIdx.x; i < 512; i += 256) {
    int n = i >> 3, kq = (i & 7) << 3;
    uint4 u;
    u.x = (unsigned)f2bf(tile[kq + 0][n]) | ((unsigned)f2bf(tile[kq + 1][n]) << 16);
    u.y = (unsigned)f2bf(tile[kq + 2][n]) | ((unsigned)f2bf(tile[kq + 3][n]) << 16);
    u.z = (unsigned)f2bf(tile[kq + 4][n]) | ((unsigned)f2bf(tile[kq + 5][n]) << 16);
    u.w = (unsigned)f2bf(tile[kq + 6][n]) | ((unsigned)f2bf(tile[kq + 7][n]) << 16);
    *(uint4*)(Wte + (size_t)(n0 + n) * 64 + kq) = u;
  }
}

// ---------------- GEMM mainloop: 2-phase double-buffered pipeline (R4-verified) ----------------
// STAGE(t+1) issued BEFORE compute(t); single __syncthreads per K-step.
// LDS: 2 buffers x (16KB A + 16KB B), ((row&7)<<4) XOR swizzle via pre-swizzled source.
__device__ __forceinline__ void gemm_mainloop(const char* __restrict__ Ab,
                                              const char* __restrict__ Bb,
                                              int kbStart, int kbEnd,
                                              size_t aBlkB, size_t bBlkB,
                                              int bm0, int bn0, char* smem,
                                              f32x4 acc[4][4]) {
  const int tid = threadIdx.x;
  const int lane = tid & 63, wid = tid >> 6;
  const int wr = wid >> 1, wc = wid & 1;
  const int lr = lane & 15, lq = lane >> 4;

  auto stage = [&](int kb, int buf) {
    const char* bA = Ab + (size_t)kb * aBlkB + (size_t)bm0 * 128;
    const char* bB = Bb + (size_t)kb * bBlkB + (size_t)bn0 * 128;
    char* sA = smem + buf * 32768;
    char* sB = sA + 16384;
#pragma unroll
    for (int r = 0; r < 4; ++r) {
      int o = r * 4096 + tid * 16;
      int row = o >> 7;
      int src = (o & ~127) | ((o & 127) ^ ((row & 7) << 4));
      __builtin_amdgcn_global_load_lds((const __attribute__((address_space(1))) void*)(bA + src),
                                       (__attribute__((address_space(3))) void*)(sA + o),
                                       16, 0, 0);
      __builtin_amdgcn_global_load_lds((const __attribute__((address_space(1))) void*)(bB + src),
                                       (__attribute__((address_space(3))) void*)(sB + o),
                                       16, 0, 0);
    }
  };

  stage(kbStart, 0);
  __syncthreads();
  int cur = 0;
  for (int kb = kbStart; kb < kbEnd; ++kb) {
    if (kb + 1 < kbEnd) stage(kb + 1, cur ^ 1);   // prefetch overlaps compute below
    char* sA = smem + cur * 32768;
    char* sB = sA + 16384;
    __builtin_amdgcn_s_setprio(1);
#pragma unroll
    for (int kk = 0; kk < 2; ++kk) {
      const int kbyte = kk * 64 + lq * 16;
      bf16x8 av[4], bv[4];
#pragma unroll
      for (int m = 0; m < 4; ++m) {
        int row = wr * 64 + m * 16 + lr;
        int off = ((row << 7) + kbyte) ^ ((lr & 7) << 4);
        av[m] = *(const bf16x8*)(sA + off);
      }
#pragma unroll
      for (int n = 0; n < 4; ++n) {
        int row = wc * 64 + n * 16 + lr;
        int off = ((row << 7) + kbyte) ^ ((lr & 7) << 4);
        bv[n] = *(const bf16x8*)(sB + off);
      }
#pragma unroll
      for (int m = 0; m < 4; ++m)
#pragma unroll
        for (int n = 0; n < 4; ++n)
          acc[m][n] = __builtin_amdgcn_mfma_f32_16x16x32_bf16(av[m], bv[n], acc[m][n], 0, 0, 0);
    }
    __builtin_amdgcn_s_setprio(0);
    __syncthreads();
    cur ^= 1;
  }
}

// ---------------- GEMM1: H_b = relu(Xd_b @ W1t_b^T + b1), bf16 blocked out ----------------
// grid 2560; XCD-chunked: one expert per XCD, m-fastest (10 blocks share a B-panel).
// Epilogue: fragments -> padded LDS tile -> coalesced 16B stores (fixes 2.5x write amp).
__global__ __launch_bounds__(256) void gemm1_kernel(const ushort_t* __restrict__ Xd,
                                                    const ushort_t* __restrict__ W1t,
                                                    const float* __restrict__ b1,
                                                    ushort_t* __restrict__ H) {
  int swz = xcd_swizzle(blockIdx.x, (NF / 128) * (CAP / 128) * NE);
  int e = swz / ((NF / 128) * (CAP / 128));
  int rem = swz % ((NF / 128) * (CAP / 128));
  int bn0 = (rem / (CAP / 128)) * 128;
  int bm0 = (rem % (CAP / 128)) * 128;
  const char* A = (const char*)(Xd + (size_t)e * CAP * ND);
  const char* B = (const char*)(W1t + (size_t)e * NF * ND);
  __shared__ __align__(16) char smem[65536];
  f32x4 zero4 = {0.f, 0.f, 0.f, 0.f};
  f32x4 acc[4][4];
#pragma unroll
  for (int m = 0; m < 4; ++m)
#pragma unroll
    for (int n = 0; n < 4; ++n) acc[m][n] = zero4;
  gemm_mainloop(A, B, 0, ND / 64, (size_t)CAP * 128, (size_t)NF * 128, bm0, bn0, smem, acc);
  const int tid = threadIdx.x;
  const int lane = tid & 63, wid = tid >> 6;
  const int wr = wid >> 1, wc = wid & 1;
  const int lr = lane & 15, lq = lane >> 4;
  // phase 1: fragments -> LDS [128][140] ushort (pad 140: scalar writes 2 lanes/bank = free)
  ushort_t* ep = (ushort_t*)smem;     // 128*140*2 = 35840 B < 64KB (mainloop done, smem free)
#pragma unroll
  for (int m = 0; m < 4; ++m) {
#pragma unroll
    for (int n = 0; n < 4; ++n) {
      int col = wc * 64 + n * 16 + lr;
      float bias = b1[(size_t)e * NF + bn0 + col];
#pragma unroll
      for (int j = 0; j < 4; ++j) {
        int row = wr * 64 + m * 16 + lq * 4 + j;
        float v = acc[m][n][j] + bias;
        v = fmaxf(v, 0.f);
        ep[row * 140 + col] = f2bf(v);
      }
    }
  }
  __syncthreads();
  // phase 2: coalesced stores of the two contiguous blocked slabs [128 rows][64 cols]
  ushort_t* He = H + (size_t)e * CAP * NF;
#pragma unroll
  for (int h = 0; h < 2; ++h) {
    ushort_t* slab = He + (size_t)((bn0 >> 6) + h) * CAP * 64 + (size_t)bm0 * 64;
#pragma unroll
    for (int it = 0; it < 4; ++it) {
      int flat = it * 2048 + tid * 8;     // ushort units; 8 threads cover one 64-col row
      int row = flat >> 6, c = flat & 63;
      uint4 u = *(const uint4*)(ep + row * 140 + h * 64 + c);
      *(uint4*)(slab + (size_t)row * 64 + c) = u;
    }
  }
}

// ---------------- GEMM2 (split-K=2): out[token] += (H_b @ W2t_b^T [+ b2]) * tprob ----------------
// grid 1280; XCD-chunked: 2 (e,s) groups per XCD, n-fastest (8 blocks share an A-panel).
// R4/R10-verified config: 149us.
__global__ __launch_bounds__(256) void gemm2_kernel(const ushort_t* __restrict__ H,
                                                    const ushort_t* __restrict__ W2t,
                                                    const float* __restrict__ b2,
                                                    const int* __restrict__ tslot,
                                                    const float* __restrict__ tprob,
                                                    float* __restrict__ out) {
  int swz = xcd_swizzle(blockIdx.x, (ND / 128) * (CAP / 128) * NE * KSPLIT);
  int z = swz / ((ND / 128) * (CAP / 128));
  int rem = swz % ((ND / 128) * (CAP / 128));
  int e = z >> 1, s = z & 1;
  int bm0 = (rem / (ND / 128)) * 128;
  int bn0 = (rem % (ND / 128)) * 128;
  const char* A = (const char*)(H + (size_t)e * CAP * NF);
  const char* B = (const char*)(W2t + (size_t)e * ND * NF);
  __shared__ __align__(16) char smem[65536];
  f32x4 zero4 = {0.f, 0.f, 0.f, 0.f};
  f32x4 acc[4][4];
#pragma unroll
  for (int m = 0; m < 4; ++m)
#pragma unroll
    for (int n = 0; n < 4; ++n) acc[m][n] = zero4;
  const int kbHalf = NF / 64 / KSPLIT;   // 32
  gemm_mainloop(A, B, s * kbHalf, (s + 1) * kbHalf, (size_t)CAP * 128, (size_t)ND * 128,
                bm0, bn0, smem, acc);
  const int lane = threadIdx.x & 63, wid = threadIdx.x >> 6;
  const int wr = wid >> 1, wc = wid & 1;
  const int lr = lane & 15, lq = lane >> 4;
  float bias[4];
#pragma unroll
  for (int n = 0; n < 4; ++n)
    bias[n] = (s == 0) ? b2[(size_t)e * ND + bn0 + wc * 64 + n * 16 + lr] : 0.f;
#pragma unroll
  for (int m = 0; m < 4; ++m) {
#pragma unroll
    for (int j = 0; j < 4; ++j) {
      int row = bm0 + wr * 64 + m * 16 + lq * 4 + j;
      int t = tslot[e * CAP + row];
      if (t >= 0) {
        float p = tprob[t];
#pragma unroll
        for (int n = 0; n < 4; ++n) {
          int col = bn0 + wc * 64 + n * 16 + lr;
          unsafeAtomicAdd(&out[(size_t)t * ND + col], (acc[m][n][j] + bias[n]) * p);
        }
      }
    }
  }
}

extern "C" void kernel_launch(void* const* d_in, const int* in_sizes, int n_in,
                              void* d_out, int out_size, void* d_ws, size_t ws_size,
                              hipStream_t stream) {
  const float* h  = (const float*)d_in[0];
  const float* gw = (const float*)d_in[1];
  const float* gb = (const float*)d_in[2];
  const float* w1 = (const float*)d_in[3];
  const float* b1 = (const float*)d_in[4];
  const float* w2 = (const float*)d_in[5];
  const float* b2 = (const float*)d_in[6];
  float* out = (float*)d_out;
  char* ws = (char*)d_ws;

  ushort_t* W1t = (ushort_t*)(ws + W1T_OFF);
  ushort_t* W2t = (ushort_t*)(ws + W2T_OFF);
  ushort_t* Xd  = (ushort_t*)(ws + XD_OFF);
  ushort_t* H   = (ushort_t*)(ws + H_OFF);
  int* eidx     = (int*)(ws + EIDX_OFF);
  float* tprob  = (float*)(ws + TPROB_OFF);
  int* tslot    = (int*)(ws + TSLOT_OFF);

  route_kernel<<<NT / 4, 256, 0, stream>>>(h, gw, gb, eidx, tprob, out);
  scan_kernel<<<1, 1024, 0, stream>>>(eidx, tslot);
  gather_kernel<<<NE * CAP, 256, 0, stream>>>(h, tslot, Xd);
  transpose_kernel<<<16384, 256, 0, stream>>>(w1, W1t, w2, W2t);
  gemm1_kernel<<<(NF / 128) * (CAP / 128) * NE, 256, 0, stream>>>(Xd, W1t, b1, H);
  gemm2_kernel<<<(ND / 128) * (CAP / 128) * NE * KSPLIT, 256, 0, stream>>>(H, W2t, b2, tslot, tprob, out);
}